// Round 5
// baseline (220.774 us; speedup 1.0000x reference)
//
#include <hip/hip_runtime.h>
#include <hip/hip_bf16.h>
#include <stdint.h>

// Problem constants
#define NUM_C 1000
#define NB    4096
#define NO    4096
#define NCOL  9192          // NB + NUM_C + NO
#define NPAD  9216          // 72 * 128
#define DK    512
#define BM    128
#define BN    128
#define INV_T 10.0f

typedef __attribute__((ext_vector_type(8))) short short8;
typedef __attribute__((ext_vector_type(4))) float f32x4;

// workspace layout (bytes)
#define OFF_FALL 0u                  // bf16 [NPAD][DK] = 9,437,184 B
#define OFF_CNT  9437184u            // uint[1024] histogram targets+pseudo
#define OFF_CNTT 9441280u            // uint[1024] histogram targets only
#define OFF_S    9445376u            // float[4096] S accumulators
#define OFF_P    9461760u            // float[4096] P accumulators
#define ZERO_BYTES 40960u            // cnt+cntT+S+P contiguous

__device__ __forceinline__ ushort f2bf_rne(float f) {
  uint32_t u = __builtin_bit_cast(uint32_t, f);
  u += 0x7FFFu + ((u >> 16) & 1u);   // round to nearest even
  return (ushort)(u >> 16);
}

// concat f32->bf16 into fall[NPAD][DK]; blocks 0..15 also build the label histograms
__global__ __launch_bounds__(256) void prep_k(const float* __restrict__ centers,
                                              const float* __restrict__ feats,
                                              const float* __restrict__ ood,
                                              const int* __restrict__ targets,
                                              const int* __restrict__ pseudo,
                                              ushort* __restrict__ fall,
                                              unsigned* __restrict__ cnt,
                                              unsigned* __restrict__ cntT) {
  int idx = blockIdx.x * 256 + threadIdx.x;   // one 8-elem chunk each; 9216*64 total
  int row = idx >> 6;
  int ck  = (idx & 63) * 8;
  ushort h[8];
  const float* src = nullptr;
  if (row < NB)              src = feats   + (size_t)row * DK + ck;
  else if (row < NB + NUM_C) src = centers + (size_t)(row - NB) * DK + ck;
  else if (row < NCOL)       src = ood     + (size_t)(row - NB - NUM_C) * DK + ck;
  if (src) {
    float4 v0 = *(const float4*)(src);
    float4 v1 = *(const float4*)(src + 4);
    h[0] = f2bf_rne(v0.x); h[1] = f2bf_rne(v0.y); h[2] = f2bf_rne(v0.z); h[3] = f2bf_rne(v0.w);
    h[4] = f2bf_rne(v1.x); h[5] = f2bf_rne(v1.y); h[6] = f2bf_rne(v1.z); h[7] = f2bf_rne(v1.w);
  } else {
    for (int i = 0; i < 8; i++) h[i] = 0;
  }
  *(uint4*)(fall + (size_t)row * DK + ck) = *(uint4*)h;

  if (blockIdx.x < 16) {
    int i = blockIdx.x * 256 + threadIdx.x;   // 0..4095
    int t = targets[i];
    atomicAdd(&cnt[t], 1u);
    atomicAdd(&cntT[t], 1u);
    atomicAdd(&cnt[pseudo[i]], 1u);
  }
}

// Fused GEMM: NO LDS staging — fragments loaded directly from global (K-major
// layout makes each MFMA fragment a contiguous 16B). Zero barriers in K-loop.
__global__ __launch_bounds__(256, 3) void gemm_fused(const ushort* __restrict__ fall,
                                                     const int* __restrict__ targets,
                                                     const int* __restrict__ pseudo,
                                                     const unsigned* __restrict__ cnt,
                                                     float* __restrict__ Sacc,
                                                     float* __restrict__ Pacc) {
  __shared__ int    sLbl[BN];
  __shared__ float  sRw0[BN];
  __shared__ float  sRw1[BN];
  __shared__ int    sTgt[BM];

  const int tid   = threadIdx.x;
  const int nTile = blockIdx.x;   // 72
  const int mTile = blockIdx.y;   // 32
  const int lane  = tid & 63;
  const int wv    = tid >> 6;     // wave 0..3
  const int wm    = wv >> 1;      // row half
  const int wn    = wv & 1;       // col half
  const int q     = lane >> 4;    // quad
  const int cIdx  = lane & 15;

  // per-column tables (lbl, 1/w, 1/(w-1)) and per-row targets
  if (tid < BN) {
    int j = nTile * BN + tid;
    int lbl, tac;
    if (j >= NCOL)         { lbl = -1; tac = -1; }
    else if (j < NB)       { tac = targets[j]; lbl = tac; }
    else if (j < NB+NUM_C) { tac = j - NB;     lbl = tac; }
    else                   { tac = pseudo[j - NB - NUM_C]; lbl = NUM_C; }
    sLbl[tid] = lbl;
    if (tac >= 0) {
      float w = (float)(cnt[tac] + 1u);
      sRw0[tid] = 1.0f / w;
      sRw1[tid] = 1.0f / (w - 1.0f);  // only selected when a positive exists => w>=2
    } else {
      sRw0[tid] = 0.f;
      sRw1[tid] = 0.f;
    }
  } else {
    sTgt[tid - 128] = targets[mTile * BM + tid - 128];
  }
  __syncthreads();   // the only barrier in the kernel

  f32x4 acc[4][4];
#pragma unroll
  for (int mi = 0; mi < 4; mi++)
#pragma unroll
    for (int ni = 0; ni < 4; ni++)
      acc[mi][ni] = (f32x4){0.f, 0.f, 0.f, 0.f};

  // lane-direct fragment pointers: A[row = mTile*128 + wm*64 + mi*16 + cIdx][k = kt*32 + q*8]
  const ushort* pA = fall + (size_t)(mTile * BM + wm * 64 + cIdx) * DK + q * 8;
  const ushort* pB = fall + (size_t)(nTile * BN + wn * 64 + cIdx) * DK + q * 8;

#pragma unroll
  for (int kt = 0; kt < DK / 32; kt++) {
    short8 af[4], bfr[4];
#pragma unroll
    for (int mi = 0; mi < 4; mi++)
      af[mi] = *(const short8*)(pA + (size_t)mi * 16 * DK + kt * 32);
#pragma unroll
    for (int ni = 0; ni < 4; ni++)
      bfr[ni] = *(const short8*)(pB + (size_t)ni * 16 * DK + kt * 32);
#pragma unroll
    for (int mi = 0; mi < 4; mi++)
#pragma unroll
      for (int ni = 0; ni < 4; ni++)
        acc[mi][ni] = __builtin_amdgcn_mfma_f32_16x16x32_bf16(af[mi], bfr[ni], acc[mi][ni], 0, 0, 0);
  }

  // Epilogue: l = acc*10; S += exp(l-10) * (diag?0 : pos?1/(w-1) : 1/w); P += pos?l:0
  float vS[16], vP[16];
#pragma unroll
  for (int s = 0; s < 16; s++) { vS[s] = 0.f; vP[s] = 0.f; }

#pragma unroll
  for (int ni = 0; ni < 4; ni++) {
    int jloc = wn * 64 + ni * 16 + cIdx;
    int j    = nTile * BN + jloc;
    int lblj = sLbl[jloc];
    float rw0 = sRw0[jloc], rw1 = sRw1[jloc];
#pragma unroll
    for (int mi = 0; mi < 4; mi++) {
      f32x4 a = acc[mi][ni];
#pragma unroll
      for (int r = 0; r < 4; r++) {
        int iloc = wm * 64 + mi * 16 + q * 4 + r;
        int i    = mTile * BM + iloc;
        int ti   = sTgt[iloc];
        float l  = a[r] * INV_T;
        bool diag = (j == i);
        bool pos  = (lblj == ti) && !diag;
        float rw  = diag ? 0.0f : (pos ? rw1 : rw0);
        float e   = __expf(l - 10.0f) * rw;
        vS[mi * 4 + r] += e;
        vP[mi * 4 + r] += pos ? l : 0.0f;
      }
    }
  }

  // fully-static value-halving butterfly over the 16 cIdx lanes (15 shuffle pairs)
#define RED_STEP(m, s, h)                                        \
  {                                                              \
    float sendS = (cIdx & (m)) ? vS[(s)] : vS[(s) + (h)];        \
    float sendP = (cIdx & (m)) ? vP[(s)] : vP[(s) + (h)];        \
    float rS = __shfl_xor(sendS, (m), 64);                       \
    float rP = __shfl_xor(sendP, (m), 64);                       \
    vS[(s)] = ((cIdx & (m)) ? vS[(s) + (h)] : vS[(s)]) + rS;     \
    vP[(s)] = ((cIdx & (m)) ? vP[(s) + (h)] : vP[(s)]) + rP;     \
  }
  RED_STEP(8, 0, 8) RED_STEP(8, 1, 8) RED_STEP(8, 2, 8) RED_STEP(8, 3, 8)
  RED_STEP(8, 4, 8) RED_STEP(8, 5, 8) RED_STEP(8, 6, 8) RED_STEP(8, 7, 8)
  RED_STEP(4, 0, 4) RED_STEP(4, 1, 4) RED_STEP(4, 2, 4) RED_STEP(4, 3, 4)
  RED_STEP(2, 0, 2) RED_STEP(2, 1, 2)
  RED_STEP(1, 0, 1)
#undef RED_STEP

  // lane (q,cIdx) holds totals for row: mi = cIdx>>2, r = cIdx&3 of its quad
  {
    int rowLoc = wm * 64 + (cIdx >> 2) * 16 + q * 4 + (cIdx & 3);
    int i = mTile * BM + rowLoc;
    atomicAdd(&Sacc[i], vS[0]);
    atomicAdd(&Pacc[i], vP[0]);
  }
}

// loss = -mean( P/npos - 10 - log S );  npos_i = cntT[targets[i]]
__global__ __launch_bounds__(256) void finalize_k(const float* __restrict__ S,
                                                  const float* __restrict__ P,
                                                  const int* __restrict__ targets,
                                                  const unsigned* __restrict__ cntT,
                                                  float* __restrict__ out) {
  __shared__ float red[4];
  int tid = threadIdx.x;
  float local = 0.f;
  for (int i = tid; i < NB; i += 256) {
    float npos = (float)cntT[targets[i]];
    local += P[i] / npos - INV_T - __logf(S[i]);
  }
  for (int m = 1; m < 64; m <<= 1) local += __shfl_xor(local, m, 64);
  if ((tid & 63) == 0) red[tid >> 6] = local;
  __syncthreads();
  if (tid == 0) {
    float t = red[0] + red[1] + red[2] + red[3];
    out[0] = -t / (float)NB;
  }
}

extern "C" void kernel_launch(void* const* d_in, const int* in_sizes, int n_in,
                              void* d_out, int out_size, void* d_ws, size_t ws_size,
                              hipStream_t stream) {
  const float* centers = (const float*)d_in[0];   // [1000][512] f32
  const float* feats   = (const float*)d_in[1];   // [4096][512] f32
  const int*   targets = (const int*)d_in[2];     // [4096] i32
  const float* ood     = (const float*)d_in[3];   // [4096][512] f32
  const int*   pseudo  = (const int*)d_in[4];     // [4096] i32

  char* ws = (char*)d_ws;
  ushort*   fall = (ushort*)(ws + OFF_FALL);
  unsigned* cnt  = (unsigned*)(ws + OFF_CNT);
  unsigned* cntT = (unsigned*)(ws + OFF_CNTT);
  float*    Sacc = (float*)(ws + OFF_S);
  float*    Pacc = (float*)(ws + OFF_P);

  hipMemsetAsync(ws + OFF_CNT, 0, ZERO_BYTES, stream);
  prep_k<<<dim3((NPAD * 64) / 256), 256, 0, stream>>>(centers, feats, ood, targets, pseudo,
                                                      fall, cnt, cntT);
  gemm_fused<<<dim3(NPAD / BN, NB / BM), 256, 0, stream>>>(fall, targets, pseudo, cnt, Sacc, Pacc);
  finalize_k<<<1, 256, 0, stream>>>(Sacc, Pacc, targets, cntT, (float*)d_out);
}

// Round 6
// 144.040 us; speedup vs baseline: 1.5327x; 1.5327x over previous
//
#include <hip/hip_runtime.h>
#include <hip/hip_bf16.h>
#include <stdint.h>

// Problem constants
#define NUM_C 1000
#define NB    4096
#define NO    4096
#define NCOL  9192          // NB + NUM_C + NO
#define NPAD  9216          // 36 * 256
#define DK    512
#define BM    128
#define BN    256
#define BK    32
#define INV_T 10.0f

typedef __attribute__((ext_vector_type(8))) short short8;
typedef __attribute__((ext_vector_type(4))) float f32x4;

// workspace layout (bytes)
#define OFF_FALL 0u                  // bf16 [NPAD][DK] = 9,437,184 B
#define OFF_CNT  9437184u            // uint[1024] histogram targets+pseudo
#define OFF_CNTT 9441280u            // uint[1024] histogram targets only
#define OFF_S    9445376u            // float[4096] S accumulators
#define OFF_P    9461760u            // float[4096] P accumulators
#define ZERO_BYTES 40960u            // cnt+cntT+S+P contiguous

__device__ __forceinline__ void async16(const void* g, void* l) {
  __builtin_amdgcn_global_load_lds((const __attribute__((address_space(1))) void*)g,
                                   (__attribute__((address_space(3))) void*)l,
                                   16, 0, 0);
}

__device__ __forceinline__ ushort f2bf_rne(float f) {
  uint32_t u = __builtin_bit_cast(uint32_t, f);
  u += 0x7FFFu + ((u >> 16) & 1u);   // round to nearest even
  return (ushort)(u >> 16);
}

// concat f32->bf16 into fall[NPAD][DK]; blocks 0..15 also build the label histograms
__global__ __launch_bounds__(256) void prep_k(const float* __restrict__ centers,
                                              const float* __restrict__ feats,
                                              const float* __restrict__ ood,
                                              const int* __restrict__ targets,
                                              const int* __restrict__ pseudo,
                                              ushort* __restrict__ fall,
                                              unsigned* __restrict__ cnt,
                                              unsigned* __restrict__ cntT) {
  int idx = blockIdx.x * 256 + threadIdx.x;   // one 8-elem chunk each; 9216*64 total
  int row = idx >> 6;
  int ck  = (idx & 63) * 8;
  ushort h[8];
  const float* src = nullptr;
  if (row < NB)              src = feats   + (size_t)row * DK + ck;
  else if (row < NB + NUM_C) src = centers + (size_t)(row - NB) * DK + ck;
  else if (row < NCOL)       src = ood     + (size_t)(row - NB - NUM_C) * DK + ck;
  if (src) {
    float4 v0 = *(const float4*)(src);
    float4 v1 = *(const float4*)(src + 4);
    h[0] = f2bf_rne(v0.x); h[1] = f2bf_rne(v0.y); h[2] = f2bf_rne(v0.z); h[3] = f2bf_rne(v0.w);
    h[4] = f2bf_rne(v1.x); h[5] = f2bf_rne(v1.y); h[6] = f2bf_rne(v1.z); h[7] = f2bf_rne(v1.w);
  } else {
    for (int i = 0; i < 8; i++) h[i] = 0;
  }
  *(uint4*)(fall + (size_t)row * DK + ck) = *(uint4*)h;

  if (blockIdx.x < 16) {
    int i = blockIdx.x * 256 + threadIdx.x;   // 0..4095
    int t = targets[i];
    atomicAdd(&cnt[t], 1u);
    atomicAdd(&cntT[t], 1u);
    atomicAdd(&cnt[pseudo[i]], 1u);
  }
}

// Fused GEMM (bf16 MFMA, m97 staging) 128x256 block tile, 64x128 wave tiles
__global__ __launch_bounds__(256, 2) void gemm_fused(const ushort* __restrict__ fall,
                                                     const int* __restrict__ targets,
                                                     const int* __restrict__ pseudo,
                                                     const unsigned* __restrict__ cnt,
                                                     float* __restrict__ Sacc,
                                                     float* __restrict__ Pacc) {
  __shared__ ushort As[BM * BK];   // [128][32] bf16, 8 KB
  __shared__ ushort Bs[BN * BK];   // [256][32] bf16, 16 KB
  __shared__ int    sLbl[BN];
  __shared__ float  sRw0[BN];
  __shared__ float  sRw1[BN];
  __shared__ int    sTgt[BM];

  const int tid   = threadIdx.x;
  const int nTile = blockIdx.x;   // 36
  const int mTile = blockIdx.y;   // 32
  const int lane  = tid & 63;
  const int wv    = tid >> 6;     // wave 0..3
  const int wm    = wv >> 1;      // row half (64 rows)
  const int wn    = wv & 1;       // col half (128 cols)
  const int q     = lane >> 4;    // quad
  const int cIdx  = lane & 15;

  // per-column tables (lbl, 1/w, 1/(w-1)); per-row targets
  {
    int j = nTile * BN + tid;     // all 256 threads: one column each
    int lbl, tac;
    if (j >= NCOL)         { lbl = -1; tac = -1; }
    else if (j < NB)       { tac = targets[j]; lbl = tac; }
    else if (j < NB+NUM_C) { tac = j - NB;     lbl = tac; }
    else                   { tac = pseudo[j - NB - NUM_C]; lbl = NUM_C; }
    sLbl[tid] = lbl;
    if (tac >= 0) {
      float w = (float)(cnt[tac] + 1u);
      sRw0[tid] = 1.0f / w;
      sRw1[tid] = 1.0f / (w - 1.0f);  // only selected when a positive exists => w>=2
    } else {
      sRw0[tid] = 0.f;
      sRw1[tid] = 0.f;
    }
    if (tid < BM) sTgt[tid] = targets[mTile * BM + tid];
  }

  f32x4 acc[4][8];
#pragma unroll
  for (int mi = 0; mi < 4; mi++)
#pragma unroll
    for (int ni = 0; ni < 8; ni++)
      acc[mi][ni] = (f32x4){0.f, 0.f, 0.f, 0.f};

  const int aRow0 = mTile * BM;
  const int bRow0 = nTile * BN;
  const int sRow  = tid >> 2;        // 0..63
  const int sKo   = (tid & 3) * 8;   // bf16 elems within the 32-wide k slab

  for (int kt = 0; kt < DK; kt += BK) {
    __syncthreads();
    // A: 128 rows (2 rounds of 64), B: 256 rows (4 rounds of 64)
    async16(fall + (size_t)(aRow0 + sRow)       * DK + kt + sKo, &As[sRow * BK + sKo]);
    async16(fall + (size_t)(aRow0 + 64 + sRow)  * DK + kt + sKo, &As[(64 + sRow) * BK + sKo]);
    async16(fall + (size_t)(bRow0 + sRow)       * DK + kt + sKo, &Bs[sRow * BK + sKo]);
    async16(fall + (size_t)(bRow0 + 64 + sRow)  * DK + kt + sKo, &Bs[(64 + sRow) * BK + sKo]);
    async16(fall + (size_t)(bRow0 + 128 + sRow) * DK + kt + sKo, &Bs[(128 + sRow) * BK + sKo]);
    async16(fall + (size_t)(bRow0 + 192 + sRow) * DK + kt + sKo, &Bs[(192 + sRow) * BK + sKo]);
    __syncthreads();

    short8 af[4], bfr[8];
#pragma unroll
    for (int mi = 0; mi < 4; mi++)
      af[mi] = *(const short8*)&As[(wm * 64 + mi * 16 + cIdx) * BK + q * 8];
#pragma unroll
    for (int ni = 0; ni < 8; ni++)
      bfr[ni] = *(const short8*)&Bs[(wn * 128 + ni * 16 + cIdx) * BK + q * 8];
#pragma unroll
    for (int mi = 0; mi < 4; mi++)
#pragma unroll
      for (int ni = 0; ni < 8; ni++)
        acc[mi][ni] = __builtin_amdgcn_mfma_f32_16x16x32_bf16(af[mi], bfr[ni], acc[mi][ni], 0, 0, 0);
  }

  // Epilogue: l = acc*10; S += exp(l-10) * (diag?0 : pos?1/(w-1) : 1/w); P += pos?l:0
  float vS[16], vP[16];
#pragma unroll
  for (int s = 0; s < 16; s++) { vS[s] = 0.f; vP[s] = 0.f; }

#pragma unroll
  for (int ni = 0; ni < 8; ni++) {
    int jloc = wn * 128 + ni * 16 + cIdx;
    int j    = nTile * BN + jloc;
    int lblj = sLbl[jloc];
    float rw0 = sRw0[jloc], rw1 = sRw1[jloc];
#pragma unroll
    for (int mi = 0; mi < 4; mi++) {
      f32x4 a = acc[mi][ni];
#pragma unroll
      for (int r = 0; r < 4; r++) {
        int iloc = wm * 64 + mi * 16 + q * 4 + r;
        int i    = mTile * BM + iloc;
        int ti   = sTgt[iloc];
        float l  = a[r] * INV_T;
        bool diag = (j == i);
        bool pos  = (lblj == ti) && !diag;
        float rw  = diag ? 0.0f : (pos ? rw1 : rw0);
        float e   = __expf(l - 10.0f) * rw;
        vS[mi * 4 + r] += e;
        vP[mi * 4 + r] += pos ? l : 0.0f;
      }
    }
  }

  // fully-static value-halving butterfly over the 16 cIdx lanes (15 shuffle pairs)
#define RED_STEP(m, s, h)                                        \
  {                                                              \
    float sendS = (cIdx & (m)) ? vS[(s)] : vS[(s) + (h)];        \
    float sendP = (cIdx & (m)) ? vP[(s)] : vP[(s) + (h)];        \
    float rS = __shfl_xor(sendS, (m), 64);                       \
    float rP = __shfl_xor(sendP, (m), 64);                       \
    vS[(s)] = ((cIdx & (m)) ? vS[(s) + (h)] : vS[(s)]) + rS;     \
    vP[(s)] = ((cIdx & (m)) ? vP[(s) + (h)] : vP[(s)]) + rP;     \
  }
  RED_STEP(8, 0, 8) RED_STEP(8, 1, 8) RED_STEP(8, 2, 8) RED_STEP(8, 3, 8)
  RED_STEP(8, 4, 8) RED_STEP(8, 5, 8) RED_STEP(8, 6, 8) RED_STEP(8, 7, 8)
  RED_STEP(4, 0, 4) RED_STEP(4, 1, 4) RED_STEP(4, 2, 4) RED_STEP(4, 3, 4)
  RED_STEP(2, 0, 2) RED_STEP(2, 1, 2)
  RED_STEP(1, 0, 1)
#undef RED_STEP

  // lane (q,cIdx) holds totals for row: mi = cIdx>>2, r = cIdx&3 of its quad
  {
    int rowLoc = wm * 64 + (cIdx >> 2) * 16 + q * 4 + (cIdx & 3);
    int i = mTile * BM + rowLoc;
    atomicAdd(&Sacc[i], vS[0]);
    atomicAdd(&Pacc[i], vP[0]);
  }
}

// loss = -mean( P/npos - 10 - log S );  npos_i = cntT[targets[i]]
__global__ __launch_bounds__(256) void finalize_k(const float* __restrict__ S,
                                                  const float* __restrict__ P,
                                                  const int* __restrict__ targets,
                                                  const unsigned* __restrict__ cntT,
                                                  float* __restrict__ out) {
  __shared__ float red[4];
  int tid = threadIdx.x;
  float local = 0.f;
  for (int i = tid; i < NB; i += 256) {
    float npos = (float)cntT[targets[i]];
    local += P[i] / npos - INV_T - __logf(S[i]);
  }
  for (int m = 1; m < 64; m <<= 1) local += __shfl_xor(local, m, 64);
  if ((tid & 63) == 0) red[tid >> 6] = local;
  __syncthreads();
  if (tid == 0) {
    float t = red[0] + red[1] + red[2] + red[3];
    out[0] = -t / (float)NB;
  }
}

extern "C" void kernel_launch(void* const* d_in, const int* in_sizes, int n_in,
                              void* d_out, int out_size, void* d_ws, size_t ws_size,
                              hipStream_t stream) {
  const float* centers = (const float*)d_in[0];   // [1000][512] f32
  const float* feats   = (const float*)d_in[1];   // [4096][512] f32
  const int*   targets = (const int*)d_in[2];     // [4096] i32
  const float* ood     = (const float*)d_in[3];   // [4096][512] f32
  const int*   pseudo  = (const int*)d_in[4];     // [4096] i32

  char* ws = (char*)d_ws;
  ushort*   fall = (ushort*)(ws + OFF_FALL);
  unsigned* cnt  = (unsigned*)(ws + OFF_CNT);
  unsigned* cntT = (unsigned*)(ws + OFF_CNTT);
  float*    Sacc = (float*)(ws + OFF_S);
  float*    Pacc = (float*)(ws + OFF_P);

  hipMemsetAsync(ws + OFF_CNT, 0, ZERO_BYTES, stream);
  prep_k<<<dim3((NPAD * 64) / 256), 256, 0, stream>>>(centers, feats, ood, targets, pseudo,
                                                      fall, cnt, cntT);
  gemm_fused<<<dim3(NPAD / BN, NB / BM), 256, 0, stream>>>(fall, targets, pseudo, cnt, Sacc, Pacc);
  finalize_k<<<1, 256, 0, stream>>>(Sacc, Pacc, targets, cntT, (float*)d_out);
}